// Round 8
// baseline (144.478 us; speedup 1.0000x reference)
//
#include <hip/hip_runtime.h>
#include <stdint.h>
#include <stddef.h>

typedef _Float16 h2 __attribute__((ext_vector_type(2)));
typedef _Float16 h8 __attribute__((ext_vector_type(8)));
typedef float f4 __attribute__((ext_vector_type(4)));

union Hfrag { h2 p[4]; h8 v; };

// ---------------- workspace layout (bytes) ----------------
// pmin/pmax (K1 partials) are dead after K2; Bt (built in K3) overlays them.
// Bt layout (STAGED-GEMM form, padded rows):
//   [ic 0..7][half 0..1][j 0..4][o 0..127][80 B row: 64 B data (kk*2) + 16 pad]
//   j = 0..3 spline cols, j = 4 base weights.  Total 1,024,000 B.
//   Row stride 80 B -> LDS bank stride 20 dwords -> uniform banks for
//   ds_read_b128 across a wave (SQ_LDS_BANK_CONFLICT == 0 measured, r6).
#define WS_PMIN   0               // f32 [512][256] = 512 KB
#define WS_PMAX   524288          // f32 [512][256] = 512 KB
#define WS_BT     0               // 1,024,000 B (overlays pmin+pmax)
#define WS_SMALL  1048576
#define WS_SCALEV (WS_SMALL + 0)      // f32 [256]
#define WS_BKN    (WS_SMALL + 1024)   // f16 [4][256] knot offsets b_j
#define WS_C0     (WS_SMALL + 3072)   // f32 [256] folded constant column
#define WS_BSC    (WS_SMALL + 4096)
#define WS_BSH    (WS_SMALL + 5120)
#define WS_SSC    (WS_SMALL + 6144)
#define WS_SSH    (WS_SMALL + 7168)

__device__ __forceinline__ void gload_lds16(const void* g, void* l) {
  __builtin_amdgcn_global_load_lds(
      (const __attribute__((address_space(1))) void*)g,
      (__attribute__((address_space(3))) void*)l, 16, 0, 0);
}

// ---------------- K1: per-feature min/max partials ----------------
__global__ __launch_bounds__(256) void kan_minmax(const float* __restrict__ x,
                                                  float* __restrict__ pmin,
                                                  float* __restrict__ pmax) {
  __shared__ f4 smn[4][64], smx[4][64];
  const int b = blockIdx.x, t = threadIdx.x;
  const int fq = t & 63, rg = t >> 6;
  const float* p = x + (size_t)b * 64 * 256 + (size_t)rg * 16 * 256 + fq * 4;
  f4 mn = (f4)(3.402823466e38f), mx = (f4)(-3.402823466e38f);
#pragma unroll
  for (int j = 0; j < 16; ++j) {
    f4 v = *(const f4*)(p + (size_t)j * 256);
    mn = __builtin_elementwise_min(mn, v);
    mx = __builtin_elementwise_max(mx, v);
  }
  smn[rg][fq] = mn; smx[rg][fq] = mx;
  __syncthreads();
  if (rg == 0) {
#pragma unroll
    for (int g = 1; g < 4; ++g) {
      mn = __builtin_elementwise_min(mn, smn[g][fq]);
      mx = __builtin_elementwise_max(mx, smx[g][fq]);
    }
    *(f4*)(pmin + (size_t)b * 256 + fq * 4) = mn;
    *(f4*)(pmax + (size_t)b * 256 + fq * 4) = mx;
  }
}

// ---------------- K2: finalize minmax -> scalev, knot offsets, BN consts ----
// 64 blocks x 256 threads; block q covers features 4q..4q+3 (f4 columns).
__global__ __launch_bounds__(256) void kan_finalize(
    const float* __restrict__ pmin, const float* __restrict__ pmax,
    const float* __restrict__ g1, const float* __restrict__ b1,
    const float* __restrict__ m1, const float* __restrict__ v1,
    const float* __restrict__ g2, const float* __restrict__ b2,
    const float* __restrict__ m2, const float* __restrict__ v2,
    float* __restrict__ scalev, _Float16* __restrict__ bkn,
    float* __restrict__ bscv, float* __restrict__ bshv,
    float* __restrict__ sscv, float* __restrict__ sshv) {
  __shared__ f4 smn[256], smx[256];
  const int t = threadIdx.x, q = blockIdx.x;
  const float* pm = pmin + (size_t)t * 256 + q * 4;
  const float* px = pmax + (size_t)t * 256 + q * 4;
  f4 mn = __builtin_elementwise_min(*(const f4*)pm, *(const f4*)(pm + 256 * 256));
  f4 mx = __builtin_elementwise_max(*(const f4*)px, *(const f4*)(px + 256 * 256));
  smn[t] = mn; smx[t] = mx;
  __syncthreads();
  for (int st = 128; st > 0; st >>= 1) {
    if (t < st) {
      smn[t] = __builtin_elementwise_min(smn[t], smn[t + st]);
      smx[t] = __builtin_elementwise_max(smx[t], smx[t + st]);
    }
    __syncthreads();
  }
  if (t == 0) {
    const f4 fmn = smn[0], fmx = smx[0];
#pragma unroll
    for (int j = 0; j < 4; ++j) {
      const int o = q * 4 + j;
      const float mnS = fmn[j], mxS = fmx[j];
      const float rng = mxS - mnS + 1e-7f;
      scalev[o] = 1.0f / rng;
      const float step = 0.25f * rng;
#pragma unroll
      for (int jj = 0; jj < 4; ++jj)
        bkn[jj * 256 + o] = (_Float16)(mnS + step * (float)jj);
      const float bs = g1[o] / sqrtf(v1[o] + 1e-3f);
      bscv[o] = bs;
      bshv[o] = b1[o] - m1[o] * bs;
      const float ss = g2[o] / sqrtf(v2[o] + 1e-3f);
      sscv[o] = ss;
      sshv[o] = b2[o] - m2[o] * ss;
    }
  }
}

// ---------------- K3: build reduced f16 weight matrix Bt + C0 ----------------
// 8 triangle bases on xn in [0,1) span {1, xn, relu(xn-1/4), relu(xn-1/2),
// relu(xn-3/4)}.  Const column -> C0 (folded into spline-BN shift); scale sc
// folds into Bt so GEMM A-columns are relu(x - b_j) on raw x (f16).
// Bt half-index = ic*64000 + half*25600 + j*5120 + o*40 + kk
//   (ic = i>>5, kk = i&31, half = og>>7, o = og&127; j=4 is base_w[i,o]).
__global__ __launch_bounds__(256) void kan_buildw(
    const float* __restrict__ spline_w, const float* __restrict__ spline_s,
    const float* __restrict__ base_w, const float* __restrict__ scalev,
    _Float16* __restrict__ Bt, float* __restrict__ C0) {
  const int og = blockIdx.x;   // 256 blocks: one output feature each
  const int i  = threadIdx.x;  // input feature
  const float* wp = spline_w + (size_t)(og * 256 + i) * 9;
  const float w1 = wp[1], w2 = wp[2], w3 = wp[3], w4 = wp[4];
  const float w5 = wp[5], w6 = wp[6], w7 = wp[7], w8 = wp[8];
  const float s  = spline_s[og * 256 + i];
  const float sc = scalev[i];
  const float wp0 = 0.25f*w1 + 0.5f*w2 + 0.75f*w3 + w4 + 0.75f*w5 + 0.5f*w6 + 0.25f*w7;
  float wj[4];
  wj[0] = (w5 + w6 + w7 + w8) - (w1 + w2 + w3 + w4);  // xn column
  wj[1] = w1 - 2.0f * w5;                             // relu(xn-1/4)
  wj[2] = w2 - 2.0f * w6;                             // relu(xn-1/2)
  wj[3] = w3 - 2.0f * w7;                             // relu(xn-3/4)
  const float ssc = s * sc;
  const int half = og >> 7, o = og & 127, ic = i >> 5, kk = i & 31;
  const size_t base = (size_t)ic * 64000 + (size_t)half * 25600 + (size_t)o * 40 + kk;
#pragma unroll
  for (int j = 0; j < 4; ++j)
    Bt[base + (size_t)j * 5120] = (_Float16)(wj[j] * ssc);
  Bt[base + 4 * 5120] = (_Float16)base_w[(size_t)i * 256 + og];
  __shared__ float red[256];
  red[i] = wp0 * s;
  __syncthreads();
  for (int st = 128; st > 0; st >>= 1) {
    if (i < st) red[i] += red[i + st];
    __syncthreads();
  }
  if (i == 0) C0[og] = red[0];
}

// ---------------- K4: fused dual GEMM + BN + SiLU (double-buffered stage) ----
// 256x128 block tile, 512 threads = 8 waves (4 wm x 2 wn), per-wave 64x64
// (the r4-proven m=4,n=4 / 16-MFMA-substep shape, byte-identical inner code).
// Grid 256 = 1 block/CU; LDS = 2 x 50 KB stage buffers + 2 KB sbkn = 104 KB.
// T3-lite schedule: STAGE(ic+1) + x-prefetch issued at chunk TOP, single
// vmcnt(0)+barrier at chunk TAIL -> stage L2 latency/BW (~900 cy) hides under
// the chunk's ~3100 cy of MFMA.  Halves stage L2 traffic vs 512 blocks.
__global__ __launch_bounds__(512, 2) void kan_gemm(
    const float* __restrict__ x, const _Float16* __restrict__ Bt,
    const _Float16* __restrict__ bkn, const float* __restrict__ C0,
    const float* __restrict__ bscv, const float* __restrict__ bshv,
    const float* __restrict__ sscv, const float* __restrict__ sshv,
    float* __restrict__ out) {
  const int tid = threadIdx.x;
  const int lane = tid & 63;
  const int wv = tid >> 6;                  // 0..7
  const int wm = wv >> 1, wn = wv & 1;
  const int lr = lane & 15, lg = lane >> 4;
  const int mt = blockIdx.x & 127, nt = blockIdx.x >> 7;

  const int rowA = mt * 256 + wm * 64 + lr;
  const int colB = wn * 64 + lr;

  __shared__ __align__(16) char smem[104448];  // 2x51200 stage + 2048 sbkn
  _Float16* sbkn = (_Float16*)(smem + 102400);
  *(uint32_t*)((char*)sbkn + tid * 4) = ((const uint32_t*)bkn)[tid];  // 512x4B

  f4 accS[4][4], accB[4][4];
#pragma unroll
  for (int m = 0; m < 4; ++m)
#pragma unroll
    for (int n = 0; n < 4; ++n) { accS[m][n] = (f4)0.0f; accB[m][n] = (f4)0.0f; }

  h2 hz; hz[0] = (_Float16)0.0f; hz[1] = (_Float16)0.0f;

  const int rowb = colB * 80 + lg * 16;        // per-lane LDS row base (bytes)

// stage chunk C into LDS buffer at byte offset BUFOFF (3200 x 16 B, linear)
#define STAGE(C, BUFOFF)                                                     \
  {                                                                          \
    const char* gsrc = (const char*)Bt + (size_t)(C) * 128000 + (size_t)nt * 51200; \
    _Pragma("unroll")                                                        \
    for (int r = 0; r < 7; ++r) {                                            \
      const int idx = r * 512 + tid;                                         \
      if (idx < 3200)                                                        \
        gload_lds16(gsrc + (size_t)idx * 16, smem + (BUFOFF) + r * 8192 + wv * 1024); \
    }                                                                        \
  }

#define LOADB(BF, J)                                                         \
  _Pragma("unroll")                                                          \
  for (int n = 0; n < 4; ++n)                                                \
    BF[n].v = *(const h8*)(sbuf + rowb + (J) * 10240 + n * 1280);

#define SPLINE_STEP(J, BF)                                                   \
  {                                                                          \
    Hfrag bbj;                                                               \
    bbj.v = *(const h8*)(sbkn + (J) * 256 + ic * 32 + lg * 8);               \
    _Pragma("unroll")                                                        \
    for (int m = 0; m < 4; ++m) {                                            \
      Hfrag afm;                                                             \
      _Pragma("unroll")                                                      \
      for (int qq = 0; qq < 4; ++qq) {                                       \
        h2 d = xh[m].p[qq] - bbj.p[qq];                                      \
        afm.p[qq] = __builtin_elementwise_max(d, hz);                        \
      }                                                                      \
      _Pragma("unroll")                                                      \
      for (int n = 0; n < 4; ++n)                                            \
        accS[m][n] = __builtin_amdgcn_mfma_f32_16x16x32_f16(afm.v, BF[n].v,  \
                                                            accS[m][n], 0, 0, 0); \
    }                                                                        \
  }

  f4 xa[4], xb[4];
  { // prologue: stage chunk 0 + x fragment for ic=0, one drain
    STAGE(0, 0)
    const int ib = lg * 8;
#pragma unroll
    for (int m = 0; m < 4; ++m) {
      const float* px = x + (size_t)(rowA + m * 16) * 256 + ib;
      xa[m] = *(const f4*)px; xb[m] = *(const f4*)(px + 4);
    }
    asm volatile("s_waitcnt vmcnt(0)" ::: "memory");
    __syncthreads();
  }

#pragma unroll 1
  for (int ic = 0; ic < 8; ++ic) {
    const char* sbuf = smem + (ic & 1) * 51200;

    // x -> f16 (RTE) FIRST (xa/xb about to be overwritten by prefetch)
    Hfrag xh[4];
#pragma unroll
    for (int m = 0; m < 4; ++m) {
      xh[m].p[0][0] = (_Float16)xa[m].x; xh[m].p[0][1] = (_Float16)xa[m].y;
      xh[m].p[1][0] = (_Float16)xa[m].z; xh[m].p[1][1] = (_Float16)xa[m].w;
      xh[m].p[2][0] = (_Float16)xb[m].x; xh[m].p[2][1] = (_Float16)xb[m].y;
      xh[m].p[3][0] = (_Float16)xb[m].z; xh[m].p[3][1] = (_Float16)xb[m].w;
    }

    // issue next chunk's stage + x prefetch NOW; drained at chunk tail only
    if (ic < 7) {
      STAGE(ic + 1, ((ic + 1) & 1) * 51200)
      const int ib = (ic + 1) * 32 + lg * 8;
#pragma unroll
      for (int m = 0; m < 4; ++m) {
        const float* px = x + (size_t)(rowA + m * 16) * 256 + ib;
        xa[m] = *(const f4*)px; xb[m] = *(const f4*)(px + 4);
      }
    }
    __builtin_amdgcn_sched_barrier(0);

    Hfrag bfA[4], bfB[4];
    LOADB(bfA, 0)
    LOADB(bfB, 1)
    SPLINE_STEP(0, bfA)
    LOADB(bfA, 2)
    SPLINE_STEP(1, bfB)
    LOADB(bfB, 3)
    SPLINE_STEP(2, bfA)
    LOADB(bfA, 4)                      // base weights
    SPLINE_STEP(3, bfB)

    // base sub-step: A = f16(x) verbatim
#pragma unroll
    for (int m = 0; m < 4; ++m)
#pragma unroll
      for (int n = 0; n < 4; ++n)
        accB[m][n] = __builtin_amdgcn_mfma_f32_16x16x32_f16(xh[m].v, bfA[n].v, accB[m][n], 0, 0, 0);

    // tail: next buffer + next x must be resident before ic+1 reads them
    __builtin_amdgcn_sched_barrier(0);
    asm volatile("s_waitcnt vmcnt(0)" ::: "memory");
    __syncthreads();
  }
#undef SPLINE_STEP
#undef LOADB
#undef STAGE

  // epilogue: out = silu(accB*bs + bsh) + accS*ss + (ssh + ss*C0)
#pragma unroll
  for (int n = 0; n < 4; ++n) {
    const int col = nt * 128 + colB + n * 16;
    const float vbs = bscv[col], vbh = bshv[col];
    const float vss = sscv[col];
    const float vsh = sshv[col] + vss * C0[col];
#pragma unroll
    for (int m = 0; m < 4; ++m) {
      const int row0 = mt * 256 + wm * 64 + m * 16 + lg * 4;
#pragma unroll
      for (int r = 0; r < 4; ++r) {
        const float zb = accB[m][n][r] * vbs + vbh;
        const float si = zb / (1.0f + __expf(-zb));
        const float val = si + accS[m][n][r] * vss + vsh;
        out[(size_t)(row0 + r) * 256 + col] = val;
      }
    }
  }
}

extern "C" void kernel_launch(void* const* d_in, const int* in_sizes, int n_in,
                              void* d_out, int out_size, void* d_ws, size_t ws_size,
                              hipStream_t stream) {
  const float* x        = (const float*)d_in[0];
  const float* base_w   = (const float*)d_in[1];
  const float* spline_w = (const float*)d_in[2];
  const float* spline_s = (const float*)d_in[3];
  const float* g1 = (const float*)d_in[4];
  const float* b1 = (const float*)d_in[5];
  const float* m1 = (const float*)d_in[6];
  const float* v1 = (const float*)d_in[7];
  const float* g2 = (const float*)d_in[8];
  const float* b2 = (const float*)d_in[9];
  const float* m2 = (const float*)d_in[10];
  const float* v2 = (const float*)d_in[11];
  float* out = (float*)d_out;
  char* ws = (char*)d_ws;

  float* pmin     = (float*)(ws + WS_PMIN);
  float* pmax     = (float*)(ws + WS_PMAX);
  _Float16* Bt    = (_Float16*)(ws + WS_BT);
  float* scalev   = (float*)(ws + WS_SCALEV);
  _Float16* bkn   = (_Float16*)(ws + WS_BKN);
  float* C0       = (float*)(ws + WS_C0);
  float* bscv     = (float*)(ws + WS_BSC);
  float* bshv     = (float*)(ws + WS_BSH);
  float* sscv     = (float*)(ws + WS_SSC);
  float* sshv     = (float*)(ws + WS_SSH);

  kan_minmax<<<512, 256, 0, stream>>>(x, pmin, pmax);
  kan_finalize<<<64, 256, 0, stream>>>(pmin, pmax, g1, b1, m1, v1, g2, b2, m2, v2,
                                       scalev, bkn, bscv, bshv, sscv, sshv);
  kan_buildw<<<256, 256, 0, stream>>>(spline_w, spline_s, base_w, scalev, Bt, C0);
  kan_gemm<<<256, 512, 0, stream>>>(x, Bt, bkn, C0, bscv, bshv, sscv, sshv, out);
}

// Round 9
// 141.754 us; speedup vs baseline: 1.0192x; 1.0192x over previous
//
#include <hip/hip_runtime.h>
#include <stdint.h>
#include <stddef.h>

typedef _Float16 h2 __attribute__((ext_vector_type(2)));
typedef _Float16 h8 __attribute__((ext_vector_type(8)));
typedef float f4 __attribute__((ext_vector_type(4)));

union Hfrag { h2 p[4]; h8 v; };

// ---------------- workspace layout (bytes) ----------------
// pmin/pmax (K1 partials) are dead after K2; Bt (built in K3) overlays them.
// Bt layout (STAGED-GEMM form, padded rows AND padded chunks):
//   [ic 0..7][half 0..1][ 57,344 B section ]
//   section: [j 0..4][o 0..127][80 B row: 64 B data + 16 pad] = 51,200 used,
//   padded to 57,344 = 7 rounds x 512 thr x 16 B so the LDS stage is exactly
//   7 gload_lds per thread (uniform count -> counted vmcnt works cross-wave).
//   Total 8*2*57,344 = 917,504 B.
#define WS_PMIN   0               // f32 [512][256] = 512 KB
#define WS_PMAX   524288          // f32 [512][256] = 512 KB
#define WS_BT     0               // 917,504 B (overlays pmin+pmax)
#define WS_SMALL  1048576
#define WS_SCALEV (WS_SMALL + 0)      // f32 [256]
#define WS_BKN    (WS_SMALL + 1024)   // f16 [4][256] knot offsets b_j
#define WS_C0     (WS_SMALL + 3072)   // f32 [256] folded constant column
#define WS_BSC    (WS_SMALL + 4096)
#define WS_BSH    (WS_SMALL + 5120)
#define WS_SSC    (WS_SMALL + 6144)
#define WS_SSH    (WS_SMALL + 7168)

__device__ __forceinline__ void gload_lds16(const void* g, void* l) {
  __builtin_amdgcn_global_load_lds(
      (const __attribute__((address_space(1))) void*)g,
      (__attribute__((address_space(3))) void*)l, 16, 0, 0);
}

// ---------------- K1: per-feature min/max partials ----------------
__global__ __launch_bounds__(256) void kan_minmax(const float* __restrict__ x,
                                                  float* __restrict__ pmin,
                                                  float* __restrict__ pmax) {
  __shared__ f4 smn[4][64], smx[4][64];
  const int b = blockIdx.x, t = threadIdx.x;
  const int fq = t & 63, rg = t >> 6;
  const float* p = x + (size_t)b * 64 * 256 + (size_t)rg * 16 * 256 + fq * 4;
  f4 mn = (f4)(3.402823466e38f), mx = (f4)(-3.402823466e38f);
#pragma unroll
  for (int j = 0; j < 16; ++j) {
    f4 v = *(const f4*)(p + (size_t)j * 256);
    mn = __builtin_elementwise_min(mn, v);
    mx = __builtin_elementwise_max(mx, v);
  }
  smn[rg][fq] = mn; smx[rg][fq] = mx;
  __syncthreads();
  if (rg == 0) {
#pragma unroll
    for (int g = 1; g < 4; ++g) {
      mn = __builtin_elementwise_min(mn, smn[g][fq]);
      mx = __builtin_elementwise_max(mx, smx[g][fq]);
    }
    *(f4*)(pmin + (size_t)b * 256 + fq * 4) = mn;
    *(f4*)(pmax + (size_t)b * 256 + fq * 4) = mx;
  }
}

// ---------------- K2: finalize minmax -> scalev, knot offsets, BN consts ----
__global__ __launch_bounds__(256) void kan_finalize(
    const float* __restrict__ pmin, const float* __restrict__ pmax,
    const float* __restrict__ g1, const float* __restrict__ b1,
    const float* __restrict__ m1, const float* __restrict__ v1,
    const float* __restrict__ g2, const float* __restrict__ b2,
    const float* __restrict__ m2, const float* __restrict__ v2,
    float* __restrict__ scalev, _Float16* __restrict__ bkn,
    float* __restrict__ bscv, float* __restrict__ bshv,
    float* __restrict__ sscv, float* __restrict__ sshv) {
  __shared__ f4 smn[256], smx[256];
  const int t = threadIdx.x, q = blockIdx.x;
  const float* pm = pmin + (size_t)t * 256 + q * 4;
  const float* px = pmax + (size_t)t * 256 + q * 4;
  f4 mn = __builtin_elementwise_min(*(const f4*)pm, *(const f4*)(pm + 256 * 256));
  f4 mx = __builtin_elementwise_max(*(const f4*)px, *(const f4*)(px + 256 * 256));
  smn[t] = mn; smx[t] = mx;
  __syncthreads();
  for (int st = 128; st > 0; st >>= 1) {
    if (t < st) {
      smn[t] = __builtin_elementwise_min(smn[t], smn[t + st]);
      smx[t] = __builtin_elementwise_max(smx[t], smx[t + st]);
    }
    __syncthreads();
  }
  if (t == 0) {
    const f4 fmn = smn[0], fmx = smx[0];
#pragma unroll
    for (int j = 0; j < 4; ++j) {
      const int o = q * 4 + j;
      const float mnS = fmn[j], mxS = fmx[j];
      const float rng = mxS - mnS + 1e-7f;
      scalev[o] = 1.0f / rng;
      const float step = 0.25f * rng;
#pragma unroll
      for (int jj = 0; jj < 4; ++jj)
        bkn[jj * 256 + o] = (_Float16)(mnS + step * (float)jj);
      const float bs = g1[o] / sqrtf(v1[o] + 1e-3f);
      bscv[o] = bs;
      bshv[o] = b1[o] - m1[o] * bs;
      const float ss = g2[o] / sqrtf(v2[o] + 1e-3f);
      sscv[o] = ss;
      sshv[o] = b2[o] - m2[o] * ss;
    }
  }
}

// ---------------- K3: build reduced f16 weight matrix Bt + C0 ----------------
// elem(ic,half,j,o,kk) = ic*57344 + half*28672 + j*5120 + o*40 + kk  (f16 units)
__global__ __launch_bounds__(256) void kan_buildw(
    const float* __restrict__ spline_w, const float* __restrict__ spline_s,
    const float* __restrict__ base_w, const float* __restrict__ scalev,
    _Float16* __restrict__ Bt, float* __restrict__ C0) {
  const int og = blockIdx.x;   // 256 blocks: one output feature each
  const int i  = threadIdx.x;  // input feature
  const float* wp = spline_w + (size_t)(og * 256 + i) * 9;
  const float w1 = wp[1], w2 = wp[2], w3 = wp[3], w4 = wp[4];
  const float w5 = wp[5], w6 = wp[6], w7 = wp[7], w8 = wp[8];
  const float s  = spline_s[og * 256 + i];
  const float sc = scalev[i];
  const float wp0 = 0.25f*w1 + 0.5f*w2 + 0.75f*w3 + w4 + 0.75f*w5 + 0.5f*w6 + 0.25f*w7;
  float wj[4];
  wj[0] = (w5 + w6 + w7 + w8) - (w1 + w2 + w3 + w4);  // xn column
  wj[1] = w1 - 2.0f * w5;                             // relu(xn-1/4)
  wj[2] = w2 - 2.0f * w6;                             // relu(xn-1/2)
  wj[3] = w3 - 2.0f * w7;                             // relu(xn-3/4)
  const float ssc = s * sc;
  const int half = og >> 7, o = og & 127, ic = i >> 5, kk = i & 31;
  const size_t base = (size_t)ic * 57344 + (size_t)half * 28672 + (size_t)o * 40 + kk;
#pragma unroll
  for (int j = 0; j < 4; ++j)
    Bt[base + (size_t)j * 5120] = (_Float16)(wj[j] * ssc);
  Bt[base + 4 * 5120] = (_Float16)base_w[(size_t)i * 256 + og];
  __shared__ float red[256];
  red[i] = wp0 * s;
  __syncthreads();
  for (int st = 128; st > 0; st >>= 1) {
    if (i < st) red[i] += red[i + st];
    __syncthreads();
  }
  if (i == 0) C0[og] = red[0];
}

// ---------------- K4: fused dual GEMM + BN + SiLU (counted-vmcnt pipeline) ---
// 256x128 block tile, 512 threads = 8 waves (4 wm x 2 wn), per-wave 64x64.
// T4 schedule (m201-style skeleton): per chunk h:
//   STAGE(h+1)[7/thread, uniform] -> s_waitcnt vmcnt(7)  (drains stage(h)+x(h),
//   LEAVES stage(h+1) in flight) -> convert x(h) -> issue x(h+1)[8] ->
//   s_barrier -> compute from buf(h) -> s_barrier.
// Never vmcnt(0) in the loop (r8's drain-per-chunk was the stall).  Counted
// waits are cross-wave-sound because every wave issues identical load counts.
__global__ __launch_bounds__(512, 2) void kan_gemm(
    const float* __restrict__ x, const _Float16* __restrict__ Bt,
    const _Float16* __restrict__ bkn, const float* __restrict__ C0,
    const float* __restrict__ bscv, const float* __restrict__ bshv,
    const float* __restrict__ sscv, const float* __restrict__ sshv,
    float* __restrict__ out) {
  const int tid = threadIdx.x;
  const int lane = tid & 63;
  const int wv = tid >> 6;                  // 0..7
  const int wm = wv >> 1, wn = wv & 1;
  const int lr = lane & 15, lg = lane >> 4;
  const int mt = blockIdx.x & 127, nt = blockIdx.x >> 7;

  const int rowA = mt * 256 + wm * 64 + lr;
  const int colB = wn * 64 + lr;

  __shared__ __align__(16) char smem[116736];  // 2 x 57344 stage + 2048 sbkn
  _Float16* sbkn = (_Float16*)(smem + 114688);
  *(uint32_t*)((char*)sbkn + tid * 4) = ((const uint32_t*)bkn)[tid];

  f4 accS[4][4], accB[4][4];
#pragma unroll
  for (int m = 0; m < 4; ++m)
#pragma unroll
    for (int n = 0; n < 4; ++n) { accS[m][n] = (f4)0.0f; accB[m][n] = (f4)0.0f; }

  h2 hz; hz[0] = (_Float16)0.0f; hz[1] = (_Float16)0.0f;

  const int rowb = colB * 80 + lg * 16;        // per-lane LDS row base (bytes)

// stage chunk C into LDS buffer BUF: exactly 7 gload_lds per thread (uniform)
#define STAGE(C, BUF)                                                        \
  {                                                                          \
    const char* gsrc = (const char*)Bt + (size_t)(C) * 114688 + (size_t)nt * 57344; \
    _Pragma("unroll")                                                        \
    for (int r = 0; r < 7; ++r)                                              \
      gload_lds16(gsrc + (size_t)(r * 512 + tid) * 16, (BUF) + r * 8192 + wv * 1024); \
  }

#define LOADB(BF, J)                                                         \
  _Pragma("unroll")                                                          \
  for (int n = 0; n < 4; ++n)                                                \
    BF[n].v = *(const h8*)(sbuf + rowb + (J) * 10240 + n * 1280);

#define SPLINE_STEP(J, BF)                                                   \
  {                                                                          \
    Hfrag bbj;                                                               \
    bbj.v = *(const h8*)(sbkn + (J) * 256 + ic * 32 + lg * 8);               \
    _Pragma("unroll")                                                        \
    for (int m = 0; m < 4; ++m) {                                            \
      Hfrag afm;                                                             \
      _Pragma("unroll")                                                      \
      for (int qq = 0; qq < 4; ++qq) {                                       \
        h2 d = xh[m].p[qq] - bbj.p[qq];                                      \
        afm.p[qq] = __builtin_elementwise_max(d, hz);                        \
      }                                                                      \
      _Pragma("unroll")                                                      \
      for (int n = 0; n < 4; ++n)                                            \
        accS[m][n] = __builtin_amdgcn_mfma_f32_16x16x32_f16(afm.v, BF[n].v,  \
                                                            accS[m][n], 0, 0, 0); \
    }                                                                        \
  }

  f4 xa[4], xb[4];
  { // prologue: stage chunk 0 + x(0); single full drain (once, cheap)
    STAGE(0, smem)
    const int ib = lg * 8;
#pragma unroll
    for (int m = 0; m < 4; ++m) {
      const float* px = x + (size_t)(rowA + m * 16) * 256 + ib;
      xa[m] = *(const f4*)px; xb[m] = *(const f4*)(px + 4);
    }
    __syncthreads();   // drains vmcnt+lgkm: stage(0), x(0), sbkn all resident
  }

#pragma unroll 1
  for (int ic = 0; ic < 8; ++ic) {
    const char* sbuf = smem + (ic & 1) * 57344;
    char* nbuf = smem + ((ic + 1) & 1) * 57344;

    // issue next chunk's stage FIRST (7 loads; protected by last chunk's
    // tail barrier -- all reads of nbuf completed there)
    if (ic < 7) STAGE(ic + 1, nbuf)
    __builtin_amdgcn_sched_barrier(0);
    // counted wait: leave stage(ic+1) in flight, drain stage(ic)+x(ic)
    if (ic < 7) asm volatile("s_waitcnt vmcnt(7)" ::: "memory");
    else        asm volatile("s_waitcnt vmcnt(0)" ::: "memory");
    __builtin_amdgcn_sched_barrier(0);

    // x(ic) now resident: convert to f16 A-layout, then reuse regs for x(ic+1)
    Hfrag xh[4];
#pragma unroll
    for (int m = 0; m < 4; ++m) {
      xh[m].p[0][0] = (_Float16)xa[m].x; xh[m].p[0][1] = (_Float16)xa[m].y;
      xh[m].p[1][0] = (_Float16)xa[m].z; xh[m].p[1][1] = (_Float16)xa[m].w;
      xh[m].p[2][0] = (_Float16)xb[m].x; xh[m].p[2][1] = (_Float16)xb[m].y;
      xh[m].p[3][0] = (_Float16)xb[m].z; xh[m].p[3][1] = (_Float16)xb[m].w;
    }
    if (ic < 7) {
      const int ib = (ic + 1) * 32 + lg * 8;
#pragma unroll
      for (int m = 0; m < 4; ++m) {
        const float* px = x + (size_t)(rowA + m * 16) * 256 + ib;
        xa[m] = *(const f4*)px; xb[m] = *(const f4*)(px + 4);
      }
    }
    __builtin_amdgcn_sched_barrier(0);
    __builtin_amdgcn_s_barrier();      // buf(ic) ready across all waves
    __builtin_amdgcn_sched_barrier(0);

    Hfrag bfA[4], bfB[4];
    LOADB(bfA, 0)
    LOADB(bfB, 1)
    SPLINE_STEP(0, bfA)
    LOADB(bfA, 2)
    SPLINE_STEP(1, bfB)
    LOADB(bfB, 3)
    SPLINE_STEP(2, bfA)
    LOADB(bfA, 4)                      // base weights
    SPLINE_STEP(3, bfB)

#pragma unroll
    for (int m = 0; m < 4; ++m)
#pragma unroll
      for (int n = 0; n < 4; ++n)
        accB[m][n] = __builtin_amdgcn_mfma_f32_16x16x32_f16(xh[m].v, bfA[n].v, accB[m][n], 0, 0, 0);

    __builtin_amdgcn_sched_barrier(0);
    __builtin_amdgcn_s_barrier();      // all reads of buf(ic) done -> next
                                       // chunk may overwrite it
  }
#undef SPLINE_STEP
#undef LOADB
#undef STAGE

  // epilogue: out = silu(accB*bs + bsh) + accS*ss + (ssh + ss*C0)
#pragma unroll
  for (int n = 0; n < 4; ++n) {
    const int col = nt * 128 + colB + n * 16;
    const float vbs = bscv[col], vbh = bshv[col];
    const float vss = sscv[col];
    const float vsh = sshv[col] + vss * C0[col];
#pragma unroll
    for (int m = 0; m < 4; ++m) {
      const int row0 = mt * 256 + wm * 64 + m * 16 + lg * 4;
#pragma unroll
      for (int r = 0; r < 4; ++r) {
        const float zb = accB[m][n][r] * vbs + vbh;
        const float si = zb / (1.0f + __expf(-zb));
        const float val = si + accS[m][n][r] * vss + vsh;
        out[(size_t)(row0 + r) * 256 + col] = val;
      }
    }
  }
}

extern "C" void kernel_launch(void* const* d_in, const int* in_sizes, int n_in,
                              void* d_out, int out_size, void* d_ws, size_t ws_size,
                              hipStream_t stream) {
  const float* x        = (const float*)d_in[0];
  const float* base_w   = (const float*)d_in[1];
  const float* spline_w = (const float*)d_in[2];
  const float* spline_s = (const float*)d_in[3];
  const float* g1 = (const float*)d_in[4];
  const float* b1 = (const float*)d_in[5];
  const float* m1 = (const float*)d_in[6];
  const float* v1 = (const float*)d_in[7];
  const float* g2 = (const float*)d_in[8];
  const float* b2 = (const float*)d_in[9];
  const float* m2 = (const float*)d_in[10];
  const float* v2 = (const float*)d_in[11];
  float* out = (float*)d_out;
  char* ws = (char*)d_ws;

  float* pmin     = (float*)(ws + WS_PMIN);
  float* pmax     = (float*)(ws + WS_PMAX);
  _Float16* Bt    = (_Float16*)(ws + WS_BT);
  float* scalev   = (float*)(ws + WS_SCALEV);
  _Float16* bkn   = (_Float16*)(ws + WS_BKN);
  float* C0       = (float*)(ws + WS_C0);
  float* bscv     = (float*)(ws + WS_BSC);
  float* bshv     = (float*)(ws + WS_BSH);
  float* sscv     = (float*)(ws + WS_SSC);
  float* sshv     = (float*)(ws + WS_SSH);

  kan_minmax<<<512, 256, 0, stream>>>(x, pmin, pmax);
  kan_finalize<<<64, 256, 0, stream>>>(pmin, pmax, g1, b1, m1, v1, g2, b2, m2, v2,
                                       scalev, bkn, bscv, bshv, sscv, sshv);
  kan_buildw<<<256, 256, 0, stream>>>(spline_w, spline_s, base_w, scalev, Bt, C0);
  kan_gemm<<<256, 512, 0, stream>>>(x, Bt, bkn, C0, bscv, bshv, sscv, sshv, out);
}